// Round 10
// baseline (116.570 us; speedup 1.0000x reference)
//
#include <hip/hip_runtime.h>
#include <hip/hip_fp16.h>

#define NN 100000
#define NE 1600000
#define NG 256
#define FIN 10
#define HID 128
#define NB 64          // pool buckets per graph
#define BKN 128        // nodes per bucket
#define NBKT 782       // ceil(NN/128)
#define FB 500         // histogram/fill blocks
#define EPB (NE / FB)  // 3200 edges per block (exact)
#define MAXE 3072      // per-bucket LDS edge staging (mean 2046, sigma 45)

struct alignas(32) HRow { __half h[16]; };  // fp16 xs row; 10 used, 32B aligned

// ---------------- kernels ----------------

// per-block LDS histogram over 782 buckets (bucket = dst >> 7); also zero pool/cntg
__global__ void k_hist(const int* __restrict__ col, int* __restrict__ H,
                       float* __restrict__ pool, float* __restrict__ cntg) {
  __shared__ int h[NBKT];
  int t = threadIdx.x, b = blockIdx.x;
  for (int k = t; k < NBKT; k += 256) h[k] = 0;
  if (b < 64) { pool[b * 256 + t] = 0.f; cntg[b * 256 + t] = 0.f; }
  __syncthreads();
  int base = b * EPB;
  for (int i = t; i < EPB; i += 256) atomicAdd(&h[col[base + i] >> 7], 1);
  __syncthreads();
  for (int k = t; k < NBKT; k += 256) H[b * NBKT + k] = h[k];
}

// per-bucket scan across the FB blocks (FB <= 512)
__global__ void k_scanA(int* __restrict__ H, int* __restrict__ btot) {
  __shared__ int tmp[512];
  int t = threadIdx.x, k = blockIdx.x;
  int v = (t < FB) ? H[t * NBKT + k] : 0;
  tmp[t] = v; __syncthreads();
  for (int off = 1; off < 512; off <<= 1) {
    int u = (t >= off) ? tmp[t - off] : 0; __syncthreads();
    tmp[t] += u; __syncthreads();
  }
  if (t < FB) H[t * NBKT + k] = tmp[t] - v;
  if (t == 511) btot[k] = tmp[511];
}

// scan bucket totals -> bucket bases (1024 threads cover 782); also v = W2 @ Wlin
__global__ void k_scanB(const int* __restrict__ btot, int* __restrict__ bbase,
                        const float* __restrict__ W2, const float* __restrict__ Wlin,
                        float* __restrict__ vbuf) {
  __shared__ int tmp[1024];
  int t = threadIdx.x;
  int v = (t < NBKT) ? btot[t] : 0;
  tmp[t] = v; __syncthreads();
  for (int off = 1; off < 1024; off <<= 1) {
    int u = (t >= off) ? tmp[t - off] : 0; __syncthreads();
    tmp[t] += u; __syncthreads();
  }
  if (t < NBKT) bbase[t] = tmp[t] - v;
  if (t < HID) {
    float a = 0.f;
    for (int o = 0; o < HID; ++o) a += W2[t * HID + o] * Wlin[o];
    vbuf[t] = a;
  }
}

// bucket the edges: LDS cursors; pack (dst&127) into src's spare bits (src < 2^17)
__global__ void k_fillb(const int* __restrict__ row, const int* __restrict__ col,
                        const float* __restrict__ w, const int* __restrict__ H,
                        const int* __restrict__ bbase, int2* __restrict__ elist) {
  __shared__ int cur[NBKT];
  int t = threadIdx.x;
  for (int k = t; k < NBKT; k += 256)
    cur[k] = bbase[k] + H[blockIdx.x * NBKT + k];
  __syncthreads();
  int base = blockIdx.x * EPB;
  for (int i = t; i < EPB; i += 256) {
    int e = base + i;
    int c = col[e];
    int p = atomicAdd(&cur[c >> 7], 1);
    elist[p] = make_int2(row[e] | ((c & 127) << 17), __float_as_int(w[e]));
  }
}

// per-bucket: LDS-staged counting sort to node-contiguous elist2; weighted degree
// -> dinv; xsh row = fp16(dinv * x), 32B padded
__global__ void __launch_bounds__(512, 4)
k_sortdeg(const int* __restrict__ bbase, const int* __restrict__ btot,
          const int2* __restrict__ elist, const float* __restrict__ x,
          int2* __restrict__ elist2, int* __restrict__ offs,
          int* __restrict__ cnt_in, float* __restrict__ dinv,
          HRow* __restrict__ xsh) {
  __shared__ int2 ebuf[MAXE];     // 24 KB staging
  __shared__ int cnt[BKN];
  __shared__ float wsum[BKN];
  __shared__ int tmp[BKN];
  __shared__ int cur[BKN];
  int k = blockIdx.x, t = threadIdx.x;
  int base = bbase[k], tot = btot[k];
  if (t < BKN) { cnt[t] = 0; wsum[t] = 0.f; }
  __syncthreads();
  bool fit = (tot <= MAXE);
  for (int i = t; i < tot; i += 512) {
    int2 ew = elist[base + i];
    if (fit) ebuf[i] = ew;
    int l = (ew.x >> 17) & 127;
    atomicAdd(&cnt[l], 1);
    atomicAdd(&wsum[l], __int_as_float(ew.y));
  }
  __syncthreads();
  int v = (t < BKN) ? cnt[t] : 0;
  if (t < BKN) tmp[t] = v;
  __syncthreads();
  for (int off = 1; off < BKN; off <<= 1) {
    int u = (t >= off && t < BKN) ? tmp[t - off] : 0;
    __syncthreads();
    if (t < BKN) tmp[t] += u;
    __syncthreads();
  }
  if (t < BKN) {
    int excl = tmp[t] - v;
    cur[t] = base + excl;
    int n = k * BKN + t;
    if (n < NN) {
      offs[n] = base + excl;
      cnt_in[n] = v;
      float di = rsqrtf(1.f + wsum[t]);
      dinv[n] = di;
      HRow r;
#pragma unroll
      for (int f = 0; f < FIN; ++f) r.h[f] = __float2half(di * x[n * FIN + f]);
#pragma unroll
      for (int f = FIN; f < 16; ++f) r.h[f] = __float2half(0.f);
      xsh[n] = r;
    }
  }
  __syncthreads();
  for (int i = t; i < tot; i += 512) {
    int2 ew = fit ? ebuf[i] : elist[base + i];
    int l = (ew.x >> 17) & 127;
    int p = atomicAdd(&cur[l], 1);
    elist2[p] = make_int2(ew.x & 0x1FFFF, ew.y);
  }
}

// 4 lanes per node: gather fp16 rows, f32 accumulate, shuffle-reduce, fused dense -> ss
__global__ void __launch_bounds__(256, 4)
k_gaxss(const int* __restrict__ offs, const int* __restrict__ cnt_in,
        const int2* __restrict__ elist2, const HRow* __restrict__ xsh,
        const float* __restrict__ x, const float* __restrict__ dinv,
        const float* __restrict__ W1, const float* __restrict__ b1,
        const float* __restrict__ vbuf, float* __restrict__ ss) {
  __shared__ float W1s[FIN * HID];
  __shared__ float b1s[HID];
  __shared__ float vs[HID];
  int t = threadIdx.x;
  for (int j = t; j < FIN * HID; j += 256) W1s[j] = W1[j];
  if (t < HID) { b1s[t] = b1[t]; vs[t] = vbuf[t]; }
  __syncthreads();
  int n = blockIdx.x * 64 + (t >> 2);
  if (n >= NN) return;
  int l = t & 3;
  int o = offs[n], cn = cnt_in[n];
  float acc[FIN];
#pragma unroll
  for (int f = 0; f < FIN; ++f) acc[f] = 0.f;
  for (int kk = l; kk < cn; kk += 4) {
    int2 ew = elist2[o + kk];
    float wt = __int_as_float(ew.y);
    const uint4* xp = (const uint4*)(xsh + (ew.x & 0x1FFFF));
    uint4 u0 = xp[0];
    unsigned u4 = ((const unsigned*)xp)[4];
    float2 p0 = __half22float2(*(const __half2*)&u0.x);
    float2 p1 = __half22float2(*(const __half2*)&u0.y);
    float2 p2 = __half22float2(*(const __half2*)&u0.z);
    float2 p3 = __half22float2(*(const __half2*)&u0.w);
    float2 p4 = __half22float2(*(const __half2*)&u4);
    acc[0] += wt * p0.x; acc[1] += wt * p0.y;
    acc[2] += wt * p1.x; acc[3] += wt * p1.y;
    acc[4] += wt * p2.x; acc[5] += wt * p2.y;
    acc[6] += wt * p3.x; acc[7] += wt * p3.y;
    acc[8] += wt * p4.x; acc[9] += wt * p4.y;
  }
#pragma unroll
  for (int f = 0; f < FIN; ++f) {
    acc[f] += __shfl_xor(acc[f], 1);
    acc[f] += __shfl_xor(acc[f], 2);
  }
  float di = dinv[n];
  float axr[FIN];
#pragma unroll
  for (int f = 0; f < FIN; ++f) axr[f] = di * (acc[f] + di * x[n * FIN + f]);
  float s = 0.f;
  for (int j = 0; j < HID / 4; ++j) {
    int h = j * 4 + l;                          // consecutive banks across lanes
    float u = b1s[h];
#pragma unroll
    for (int f = 0; f < FIN; ++f) u += axr[f] * W1s[f * HID + h];
    s += fmaxf(u, 0.f) * vs[h];
  }
  s += __shfl_xor(s, 1);
  s += __shfl_xor(s, 2);
  if (l == 0) ss[n] = di * s;
}

// 4 lanes per node: pool[g] += dinv_n * ( ss[n] + sum_e w_e * ss[src] ); counts
__global__ void k_gpool(const int* __restrict__ offs, const int* __restrict__ cnt_in,
                        const int2* __restrict__ elist2, const float* __restrict__ ss,
                        const float* __restrict__ dinv, const int* __restrict__ batch,
                        float* __restrict__ pool, float* __restrict__ cntg) {
  int t = threadIdx.x;
  int n = blockIdx.x * 64 + (t >> 2);
  if (n >= NN) return;
  int l = t & 3;
  int o = offs[n], cn = cnt_in[n];
  float acc = 0.f;
  for (int kk = l; kk < cn; kk += 4) {
    int2 ew = elist2[o + kk];
    acc += __int_as_float(ew.y) * ss[ew.x];
  }
  acc += __shfl_xor(acc, 1);
  acc += __shfl_xor(acc, 2);
  if (l == 0) {
    acc += ss[n];
    int bk = (n ^ (n >> 6)) & (NB - 1);
    atomicAdd(&pool[batch[n] * NB + bk], dinv[n] * acc);
    atomicAdd(&cntg[batch[n] * NB + bk], 1.f);
  }
}

__global__ void k_final(const float* __restrict__ pool, const float* __restrict__ cntg,
                        const float* __restrict__ b2, const float* __restrict__ Wlin,
                        const float* __restrict__ blin, float* __restrict__ out) {
  int g = blockIdx.x * blockDim.x + threadIdx.x;
  if (g < NG) {
    float cc = blin[0];
    for (int o = 0; o < HID; ++o) cc += b2[o] * Wlin[o];
    float ps = 0.f, cs = 0.f;
    for (int b = 0; b < NB; ++b) { ps += pool[g * NB + b]; cs += cntg[g * NB + b]; }
    out[g] = ps / fmaxf(cs, 1.0f) + cc;
  }
}

// ---------------- launch ----------------

extern "C" void kernel_launch(void* const* d_in, const int* in_sizes, int n_in,
                              void* d_out, int out_size, void* d_ws, size_t ws_size,
                              hipStream_t stream) {
  const float* x     = (const float*)d_in[0];
  const int*   ei    = (const int*)d_in[1];
  const float* w     = (const float*)d_in[2];
  const int*   batch = (const int*)d_in[3];
  const float* W1    = (const float*)d_in[4];
  const float* b1    = (const float*)d_in[5];
  const float* W2    = (const float*)d_in[6];
  const float* b2    = (const float*)d_in[7];
  const float* Wlin  = (const float*)d_in[8];
  const float* blin  = (const float*)d_in[9];
  float* out = (float*)d_out;

  const int* row = ei;
  const int* col = ei + NE;

  // workspace layout (32B-aligned chunks)
  char* p = (char*)d_ws;
  int2*  elist  = (int2*)p;  p += sizeof(int2) * NE;        // 12.8 MB
  int2*  elist2 = (int2*)p;  p += sizeof(int2) * NE;        // 12.8 MB
  HRow*  xsh    = (HRow*)p;  p += sizeof(HRow) * NN;        // 3.2 MB
  int*   H      = (int*)p;   p += sizeof(int) * (FB * NBKT + 1024);  // ~1.57 MB
  int*   btot   = (int*)p;   p += sizeof(int) * 1024;
  int*   bbase  = (int*)p;   p += sizeof(int) * 1024;
  int*   offs   = (int*)p;   p += sizeof(int) * NN;
  int*   cnt_in = (int*)p;   p += sizeof(int) * NN;
  float* dinv   = (float*)p; p += sizeof(float) * NN;
  float* ss     = (float*)p; p += sizeof(float) * NN;
  float* vbuf   = (float*)p; p += sizeof(float) * HID;
  float* pool   = (float*)p; p += sizeof(float) * NG * NB;
  float* cntg   = (float*)p; p += sizeof(float) * NG * NB;

  const int gN4 = (NN + 63) / 64;    // 1563 blocks for 4-lane-per-node kernels

  hipLaunchKernelGGL(k_hist,    dim3(FB),   dim3(256), 0, stream, col, H, pool, cntg);
  hipLaunchKernelGGL(k_scanA,   dim3(NBKT), dim3(512), 0, stream, H, btot);
  hipLaunchKernelGGL(k_scanB,   dim3(1),    dim3(1024), 0, stream, btot, bbase, W2, Wlin, vbuf);
  hipLaunchKernelGGL(k_fillb,   dim3(FB),   dim3(256), 0, stream, row, col, w, H, bbase, elist);
  hipLaunchKernelGGL(k_sortdeg, dim3(NBKT), dim3(512), 0, stream, bbase, btot, elist, x,
                     elist2, offs, cnt_in, dinv, xsh);
  hipLaunchKernelGGL(k_gaxss,   dim3(gN4),  dim3(256), 0, stream, offs, cnt_in, elist2, xsh,
                     x, dinv, W1, b1, vbuf, ss);
  hipLaunchKernelGGL(k_gpool,   dim3(gN4),  dim3(256), 0, stream, offs, cnt_in, elist2, ss,
                     dinv, batch, pool, cntg);
  hipLaunchKernelGGL(k_final,   dim3(1),    dim3(256), 0, stream, pool, cntg, b2, Wlin, blin, out);
}

// Round 11
// 115.743 us; speedup vs baseline: 1.0071x; 1.0071x over previous
//
#include <hip/hip_runtime.h>
#include <hip/hip_fp16.h>

#define NN 100000
#define NE 1600000
#define NG 256
#define FIN 10
#define HID 128
#define NB 64          // pool buckets per graph
#define NBKT 391       // coarse buckets of 256 nodes: ceil(NN/256)
#define FB 500         // histogram/fill blocks
#define EPB (NE / FB)  // 3200 edges per block (exact)

struct alignas(32) HRow { __half h[16]; };  // fp16 xs row; 10 used, 32B aligned

// ---------------- kernels ----------------

// per-block LDS histogram over 391 buckets (bucket = dst >> 8); also zero pool
__global__ void k_hist(const int* __restrict__ col, int* __restrict__ H,
                       float* __restrict__ pool) {
  __shared__ int h[NBKT];
  int t = threadIdx.x, b = blockIdx.x;
  for (int k = t; k < NBKT; k += 256) h[k] = 0;
  if (b < 64) pool[b * 256 + t] = 0.f;
  __syncthreads();
  int base = b * EPB;
  for (int i = t; i < EPB; i += 256) atomicAdd(&h[col[base + i] >> 8], 1);
  __syncthreads();
  for (int k = t; k < NBKT; k += 256) H[b * NBKT + k] = h[k];
}

// per-bucket scan across the FB blocks (FB <= 512); block 0 also computes v = W2@Wlin
__global__ void k_scanA(int* __restrict__ H, int* __restrict__ btot,
                        const float* __restrict__ W2, const float* __restrict__ Wlin,
                        float* __restrict__ vbuf) {
  __shared__ int tmp[512];
  int t = threadIdx.x, k = blockIdx.x;
  int v = (t < FB) ? H[t * NBKT + k] : 0;
  tmp[t] = v; __syncthreads();
  for (int off = 1; off < 512; off <<= 1) {
    int u = (t >= off) ? tmp[t - off] : 0; __syncthreads();
    tmp[t] += u; __syncthreads();
  }
  if (t < FB) H[t * NBKT + k] = tmp[t] - v;
  if (t == 511) btot[k] = tmp[511];
  if (k == 0 && t < HID) {
    float a = 0.f;
    for (int o = 0; o < HID; ++o) a += W2[t * HID + o] * Wlin[o];
    vbuf[t] = a;
  }
}

// bucket the edges: in-block bucket-base scan from btot; LDS cursors;
// pack (dst&255) into src's spare bits (src < 2^17)
__global__ void k_fillb(const int* __restrict__ row, const int* __restrict__ col,
                        const float* __restrict__ w, const int* __restrict__ H,
                        const int* __restrict__ btot, int2* __restrict__ elist) {
  __shared__ int tmp[512];
  __shared__ int cur[NBKT];
  int t = threadIdx.x;
  // exclusive scan of btot -> bucket bases (Hillis-Steele over 512 >= NBKT)
  int v = (t < NBKT) ? btot[t] : 0;
  tmp[t] = v; __syncthreads();
  for (int off = 1; off < 512; off <<= 1) {
    int u = (t >= off) ? tmp[t - off] : 0; __syncthreads();
    tmp[t] += u; __syncthreads();
  }
  if (t < NBKT) cur[t] = (tmp[t] - v) + H[blockIdx.x * NBKT + t];
  __syncthreads();
  int base = blockIdx.x * EPB;
  for (int i = t; i < EPB; i += 512) {
    int e = base + i;
    int c = col[e];
    int p = atomicAdd(&cur[c >> 8], 1);
    elist[p] = make_int2(row[e] | ((c & 255) << 17), __float_as_int(w[e]));
  }
}

// per-bucket: LDS counting sort to node-contiguous elist2; weighted degree -> dinv;
// xsh row = fp16(dinv * x), 32B padded. Bucket base recomputed in-block.
__global__ void k_sortdeg(const int* __restrict__ btot, const int2* __restrict__ elist,
                          const float* __restrict__ x, int2* __restrict__ elist2,
                          int* __restrict__ offs, int* __restrict__ cnt_in,
                          float* __restrict__ dinv, HRow* __restrict__ xsh) {
  __shared__ int stmp[512];
  __shared__ int cnt[256];
  __shared__ float wsum[256];
  __shared__ int tmp[256];
  __shared__ int cur[256];
  int k = blockIdx.x, t = threadIdx.x;
  // base = sum btot[0..k-1], tot = btot[k]
  int v0 = (t < NBKT) ? btot[t] : 0;
  stmp[t] = v0; __syncthreads();
  for (int off = 1; off < 512; off <<= 1) {
    int u = (t >= off) ? stmp[t - off] : 0; __syncthreads();
    stmp[t] += u; __syncthreads();
  }
  int base = stmp[k] - btot[k];
  int tot = btot[k];
  if (t < 256) { cnt[t] = 0; wsum[t] = 0.f; }
  __syncthreads();
  for (int i = t; i < tot; i += 512) {
    int2 ew = elist[base + i];
    int l = (ew.x >> 17) & 255;
    atomicAdd(&cnt[l], 1);
    atomicAdd(&wsum[l], __int_as_float(ew.y));
  }
  __syncthreads();
  int v = (t < 256) ? cnt[t] : 0;
  if (t < 256) tmp[t] = v;
  __syncthreads();
  for (int off = 1; off < 256; off <<= 1) {
    int u = (t >= off && t < 256) ? tmp[t - off] : 0;
    __syncthreads();
    if (t < 256) tmp[t] += u;
    __syncthreads();
  }
  if (t < 256) {
    int excl = tmp[t] - v;
    cur[t] = base + excl;
    int n = (k << 8) + t;
    if (n < NN) {
      offs[n] = base + excl;
      cnt_in[n] = v;
      float di = rsqrtf(1.f + wsum[t]);
      dinv[n] = di;
      HRow r;
#pragma unroll
      for (int f = 0; f < FIN; ++f) r.h[f] = __float2half(di * x[n * FIN + f]);
#pragma unroll
      for (int f = FIN; f < 16; ++f) r.h[f] = __float2half(0.f);
      xsh[n] = r;
    }
  }
  __syncthreads();
  for (int i = t; i < tot; i += 512) {
    int2 ew = elist[base + i];
    int l = (ew.x >> 17) & 255;
    int p = atomicAdd(&cur[l], 1);
    elist2[p] = make_int2(ew.x & 0x1FFFF, ew.y);
  }
}

// 4 lanes per node: gather fp16 rows, f32 accumulate, shuffle-reduce, fused dense -> ss
__global__ void __launch_bounds__(256, 4)
k_gaxss(const int* __restrict__ offs, const int* __restrict__ cnt_in,
        const int2* __restrict__ elist2, const HRow* __restrict__ xsh,
        const float* __restrict__ x, const float* __restrict__ dinv,
        const float* __restrict__ W1, const float* __restrict__ b1,
        const float* __restrict__ vbuf, float* __restrict__ ss) {
  __shared__ float W1s[FIN * HID];
  __shared__ float b1s[HID];
  __shared__ float vs[HID];
  int t = threadIdx.x;
  for (int j = t; j < FIN * HID; j += 256) W1s[j] = W1[j];
  if (t < HID) { b1s[t] = b1[t]; vs[t] = vbuf[t]; }
  __syncthreads();
  int n = blockIdx.x * 64 + (t >> 2);
  if (n >= NN) return;
  int l = t & 3;
  int o = offs[n], cn = cnt_in[n];
  float acc[FIN];
#pragma unroll
  for (int f = 0; f < FIN; ++f) acc[f] = 0.f;
  for (int kk = l; kk < cn; kk += 4) {
    int2 ew = elist2[o + kk];
    float wt = __int_as_float(ew.y);
    const uint4* xp = (const uint4*)(xsh + (ew.x & 0x1FFFF));
    uint4 u0 = xp[0];
    unsigned u4 = ((const unsigned*)xp)[4];
    float2 p0 = __half22float2(*(const __half2*)&u0.x);
    float2 p1 = __half22float2(*(const __half2*)&u0.y);
    float2 p2 = __half22float2(*(const __half2*)&u0.z);
    float2 p3 = __half22float2(*(const __half2*)&u0.w);
    float2 p4 = __half22float2(*(const __half2*)&u4);
    acc[0] += wt * p0.x; acc[1] += wt * p0.y;
    acc[2] += wt * p1.x; acc[3] += wt * p1.y;
    acc[4] += wt * p2.x; acc[5] += wt * p2.y;
    acc[6] += wt * p3.x; acc[7] += wt * p3.y;
    acc[8] += wt * p4.x; acc[9] += wt * p4.y;
  }
#pragma unroll
  for (int f = 0; f < FIN; ++f) {
    acc[f] += __shfl_xor(acc[f], 1);
    acc[f] += __shfl_xor(acc[f], 2);
  }
  float di = dinv[n];
  float axr[FIN];
#pragma unroll
  for (int f = 0; f < FIN; ++f) axr[f] = di * (acc[f] + di * x[n * FIN + f]);
  float s = 0.f;
  for (int j = 0; j < HID / 4; ++j) {
    int h = j * 4 + l;                          // consecutive banks across lanes
    float u = b1s[h];
#pragma unroll
    for (int f = 0; f < FIN; ++f) u += axr[f] * W1s[f * HID + h];
    s += fmaxf(u, 0.f) * vs[h];
  }
  s += __shfl_xor(s, 1);
  s += __shfl_xor(s, 2);
  if (l == 0) ss[n] = di * s;
}

// 4 lanes per node: pool[g] += dinv_n * ( ss[n] + sum_e w_e * ss[src] )
__global__ void k_gpool(const int* __restrict__ offs, const int* __restrict__ cnt_in,
                        const int2* __restrict__ elist2, const float* __restrict__ ss,
                        const float* __restrict__ dinv, const int* __restrict__ batch,
                        float* __restrict__ pool) {
  int t = threadIdx.x;
  int n = blockIdx.x * 64 + (t >> 2);
  if (n >= NN) return;
  int l = t & 3;
  int o = offs[n], cn = cnt_in[n];
  float acc = 0.f;
  for (int kk = l; kk < cn; kk += 4) {
    int2 ew = elist2[o + kk];
    acc += __int_as_float(ew.y) * ss[ew.x];
  }
  acc += __shfl_xor(acc, 1);
  acc += __shfl_xor(acc, 2);
  if (l == 0) {
    acc += ss[n];
    int bk = (n ^ (n >> 6)) & (NB - 1);
    atomicAdd(&pool[batch[n] * NB + bk], dinv[n] * acc);
  }
}

// per-graph counts via binary search on the SORTED batch array; reduce pool buckets
__global__ void k_final(const float* __restrict__ pool, const int* __restrict__ batch,
                        const float* __restrict__ b2, const float* __restrict__ Wlin,
                        const float* __restrict__ blin, float* __restrict__ out) {
  int g = threadIdx.x;  // 256 threads
  if (g < NG) {
    // lower_bound(batch, g) and lower_bound(batch, g+1)
    int lo = 0, hi = NN;
    while (lo < hi) { int m = (lo + hi) >> 1; if (batch[m] < g) lo = m + 1; else hi = m; }
    int lb = lo;
    hi = NN;
    while (lo < hi) { int m = (lo + hi) >> 1; if (batch[m] < g + 1) lo = m + 1; else hi = m; }
    float cs = (float)(lo - lb);
    float cc = blin[0];
    for (int o = 0; o < HID; ++o) cc += b2[o] * Wlin[o];
    float ps = 0.f;
    for (int b = 0; b < NB; ++b) ps += pool[g * NB + b];
    out[g] = ps / fmaxf(cs, 1.0f) + cc;
  }
}

// ---------------- launch ----------------

extern "C" void kernel_launch(void* const* d_in, const int* in_sizes, int n_in,
                              void* d_out, int out_size, void* d_ws, size_t ws_size,
                              hipStream_t stream) {
  const float* x     = (const float*)d_in[0];
  const int*   ei    = (const int*)d_in[1];
  const float* w     = (const float*)d_in[2];
  const int*   batch = (const int*)d_in[3];
  const float* W1    = (const float*)d_in[4];
  const float* b1    = (const float*)d_in[5];
  const float* W2    = (const float*)d_in[6];
  const float* b2    = (const float*)d_in[7];
  const float* Wlin  = (const float*)d_in[8];
  const float* blin  = (const float*)d_in[9];
  float* out = (float*)d_out;

  const int* row = ei;
  const int* col = ei + NE;

  // workspace layout (32B-aligned chunks)
  char* p = (char*)d_ws;
  int2*  elist  = (int2*)p;  p += sizeof(int2) * NE;        // 12.8 MB
  int2*  elist2 = (int2*)p;  p += sizeof(int2) * NE;        // 12.8 MB
  HRow*  xsh    = (HRow*)p;  p += sizeof(HRow) * NN;        // 3.2 MB
  int*   H      = (int*)p;   p += sizeof(int) * (FB * NBKT + 512);  // ~0.78 MB
  int*   btot   = (int*)p;   p += sizeof(int) * 512;
  int*   offs   = (int*)p;   p += sizeof(int) * NN;
  int*   cnt_in = (int*)p;   p += sizeof(int) * NN;
  float* dinv   = (float*)p; p += sizeof(float) * NN;
  float* ss     = (float*)p; p += sizeof(float) * NN;
  float* vbuf   = (float*)p; p += sizeof(float) * HID;
  float* pool   = (float*)p; p += sizeof(float) * NG * NB;

  const int gN4 = (NN + 63) / 64;    // 1563 blocks for 4-lane-per-node kernels

  hipLaunchKernelGGL(k_hist,    dim3(FB),   dim3(256), 0, stream, col, H, pool);
  hipLaunchKernelGGL(k_scanA,   dim3(NBKT), dim3(512), 0, stream, H, btot, W2, Wlin, vbuf);
  hipLaunchKernelGGL(k_fillb,   dim3(FB),   dim3(512), 0, stream, row, col, w, H, btot, elist);
  hipLaunchKernelGGL(k_sortdeg, dim3(NBKT), dim3(512), 0, stream, btot, elist, x,
                     elist2, offs, cnt_in, dinv, xsh);
  hipLaunchKernelGGL(k_gaxss,   dim3(gN4),  dim3(256), 0, stream, offs, cnt_in, elist2, xsh,
                     x, dinv, W1, b1, vbuf, ss);
  hipLaunchKernelGGL(k_gpool,   dim3(gN4),  dim3(256), 0, stream, offs, cnt_in, elist2, ss,
                     dinv, batch, pool);
  hipLaunchKernelGGL(k_final,   dim3(1),    dim3(256), 0, stream, pool, batch, b2, Wlin, blin, out);
}

// Round 12
// 110.259 us; speedup vs baseline: 1.0572x; 1.0497x over previous
//
#include <hip/hip_runtime.h>
#include <hip/hip_fp16.h>

#define NN 100000
#define NE 1600000
#define NG 256
#define FIN 10
#define HID 128
#define NB 64          // pool buckets per graph
#define NBKT 391       // coarse buckets of 256 nodes: ceil(NN/256)
#define FB 500         // fill blocks
#define EPB (NE / FB)  // 3200 edges per block (exact)
#define CAP 5120       // fixed bucket capacity (mean 4092, sigma 64 -> 16 sigma)

struct alignas(32) HRow { __half h[16]; };  // fp16 xs row; 10 used, 32B aligned

// ---------------- kernels ----------------

// zero pool + bucket cursors; block 0 computes v = W2 @ Wlin
__global__ void k_zero(float* __restrict__ pool, int* __restrict__ gcur,
                       const float* __restrict__ W2, const float* __restrict__ Wlin,
                       float* __restrict__ vbuf) {
  int t = threadIdx.x, b = blockIdx.x;
  if (b < 64) pool[b * 256 + t] = 0.f;
  if (b == 64) { for (int k = t; k < NBKT; k += 256) gcur[k] = 0; }
  if (b == 65 && t < HID) {
    float a = 0.f;
    for (int o = 0; o < HID; ++o) a += W2[t * HID + o] * Wlin[o];
    vbuf[t] = a;
  }
}

// single-pass bucketing: LDS-stage edges + LDS hist, claim per-bucket base via one
// global atomic per (block,bucket), scatter from LDS into fixed bucket regions.
// pack (dst&255) into src's spare bits (src < 2^17)
__global__ void __launch_bounds__(512)
k_fillb2(const int* __restrict__ row, const int* __restrict__ col,
         const float* __restrict__ w, int* __restrict__ gcur,
         int2* __restrict__ elist) {
  __shared__ int2 ebuf[EPB];       // 25.6 KB
  __shared__ short sbkt[EPB];      // 6.4 KB
  __shared__ int h[NBKT];
  __shared__ int base[NBKT];
  __shared__ int cur[NBKT];
  int t = threadIdx.x;
  for (int k = t; k < NBKT; k += 512) { h[k] = 0; cur[k] = 0; }
  __syncthreads();
  int gb = blockIdx.x * EPB;
  for (int i = t; i < EPB; i += 512) {
    int e = gb + i;
    int c = col[e];
    ebuf[i] = make_int2(row[e] | ((c & 255) << 17), __float_as_int(w[e]));
    sbkt[i] = (short)(c >> 8);
    atomicAdd(&h[c >> 8], 1);
  }
  __syncthreads();
  for (int k = t; k < NBKT; k += 512) {
    int hv = h[k];
    base[k] = hv ? atomicAdd(&gcur[k], hv) : 0;
  }
  __syncthreads();
  for (int i = t; i < EPB; i += 512) {
    int bkt = sbkt[i];
    int p = atomicAdd(&cur[bkt], 1);
    elist[(size_t)bkt * CAP + base[bkt] + p] = ebuf[i];
  }
}

// per-bucket: LDS counting sort to node-contiguous elist2 (fixed regions);
// weighted degree -> dinv; xsh row = fp16(dinv * x), 32B padded
__global__ void k_sortdeg(const int* __restrict__ gcur, const int2* __restrict__ elist,
                          const float* __restrict__ x, int2* __restrict__ elist2,
                          int* __restrict__ offs, int* __restrict__ cnt_in,
                          float* __restrict__ dinv, HRow* __restrict__ xsh) {
  __shared__ int cnt[256];
  __shared__ float wsum[256];
  __shared__ int tmp[256];
  __shared__ int cur[256];
  int k = blockIdx.x, t = threadIdx.x;
  size_t base = (size_t)k * CAP;
  int tot = gcur[k];
  if (t < 256) { cnt[t] = 0; wsum[t] = 0.f; }
  __syncthreads();
  for (int i = t; i < tot; i += 512) {
    int2 ew = elist[base + i];
    int l = (ew.x >> 17) & 255;
    atomicAdd(&cnt[l], 1);
    atomicAdd(&wsum[l], __int_as_float(ew.y));
  }
  __syncthreads();
  int v = (t < 256) ? cnt[t] : 0;
  if (t < 256) tmp[t] = v;
  __syncthreads();
  for (int off = 1; off < 256; off <<= 1) {
    int u = (t >= off && t < 256) ? tmp[t - off] : 0;
    __syncthreads();
    if (t < 256) tmp[t] += u;
    __syncthreads();
  }
  if (t < 256) {
    int excl = tmp[t] - v;
    cur[t] = (int)(base + excl) ;
    int n = (k << 8) + t;
    if (n < NN) {
      offs[n] = (int)(base + excl);
      cnt_in[n] = v;
      float di = rsqrtf(1.f + wsum[t]);
      dinv[n] = di;
      HRow r;
#pragma unroll
      for (int f = 0; f < FIN; ++f) r.h[f] = __float2half(di * x[n * FIN + f]);
#pragma unroll
      for (int f = FIN; f < 16; ++f) r.h[f] = __float2half(0.f);
      xsh[n] = r;
    }
  }
  __syncthreads();
  for (int i = t; i < tot; i += 512) {
    int2 ew = elist[base + i];
    int l = (ew.x >> 17) & 255;
    int p = atomicAdd(&cur[l], 1);
    elist2[p] = make_int2(ew.x & 0x1FFFF, ew.y);
  }
}

// 4 lanes per node: gather fp16 rows, f32 accumulate, shuffle-reduce, fused dense -> ss
__global__ void __launch_bounds__(256, 4)
k_gaxss(const int* __restrict__ offs, const int* __restrict__ cnt_in,
        const int2* __restrict__ elist2, const HRow* __restrict__ xsh,
        const float* __restrict__ x, const float* __restrict__ dinv,
        const float* __restrict__ W1, const float* __restrict__ b1,
        const float* __restrict__ vbuf, float* __restrict__ ss) {
  __shared__ float W1s[FIN * HID];
  __shared__ float b1s[HID];
  __shared__ float vs[HID];
  int t = threadIdx.x;
  for (int j = t; j < FIN * HID; j += 256) W1s[j] = W1[j];
  if (t < HID) { b1s[t] = b1[t]; vs[t] = vbuf[t]; }
  __syncthreads();
  int n = blockIdx.x * 64 + (t >> 2);
  if (n >= NN) return;
  int l = t & 3;
  int o = offs[n], cn = cnt_in[n];
  float acc[FIN];
#pragma unroll
  for (int f = 0; f < FIN; ++f) acc[f] = 0.f;
  for (int kk = l; kk < cn; kk += 4) {
    int2 ew = elist2[o + kk];
    float wt = __int_as_float(ew.y);
    const uint4* xp = (const uint4*)(xsh + (ew.x & 0x1FFFF));
    uint4 u0 = xp[0];
    unsigned u4 = ((const unsigned*)xp)[4];
    float2 p0 = __half22float2(*(const __half2*)&u0.x);
    float2 p1 = __half22float2(*(const __half2*)&u0.y);
    float2 p2 = __half22float2(*(const __half2*)&u0.z);
    float2 p3 = __half22float2(*(const __half2*)&u0.w);
    float2 p4 = __half22float2(*(const __half2*)&u4);
    acc[0] += wt * p0.x; acc[1] += wt * p0.y;
    acc[2] += wt * p1.x; acc[3] += wt * p1.y;
    acc[4] += wt * p2.x; acc[5] += wt * p2.y;
    acc[6] += wt * p3.x; acc[7] += wt * p3.y;
    acc[8] += wt * p4.x; acc[9] += wt * p4.y;
  }
#pragma unroll
  for (int f = 0; f < FIN; ++f) {
    acc[f] += __shfl_xor(acc[f], 1);
    acc[f] += __shfl_xor(acc[f], 2);
  }
  float di = dinv[n];
  float axr[FIN];
#pragma unroll
  for (int f = 0; f < FIN; ++f) axr[f] = di * (acc[f] + di * x[n * FIN + f]);
  float s = 0.f;
  for (int j = 0; j < HID / 4; ++j) {
    int h = j * 4 + l;                          // consecutive banks across lanes
    float u = b1s[h];
#pragma unroll
    for (int f = 0; f < FIN; ++f) u += axr[f] * W1s[f * HID + h];
    s += fmaxf(u, 0.f) * vs[h];
  }
  s += __shfl_xor(s, 1);
  s += __shfl_xor(s, 2);
  if (l == 0) ss[n] = di * s;
}

// 4 lanes per node: pool[g] += dinv_n * ( ss[n] + sum_e w_e * ss[src] )
__global__ void k_gpool(const int* __restrict__ offs, const int* __restrict__ cnt_in,
                        const int2* __restrict__ elist2, const float* __restrict__ ss,
                        const float* __restrict__ dinv, const int* __restrict__ batch,
                        float* __restrict__ pool) {
  int t = threadIdx.x;
  int n = blockIdx.x * 64 + (t >> 2);
  if (n >= NN) return;
  int l = t & 3;
  int o = offs[n], cn = cnt_in[n];
  float acc = 0.f;
  for (int kk = l; kk < cn; kk += 4) {
    int2 ew = elist2[o + kk];
    acc += __int_as_float(ew.y) * ss[ew.x];
  }
  acc += __shfl_xor(acc, 1);
  acc += __shfl_xor(acc, 2);
  if (l == 0) {
    acc += ss[n];
    int bk = (n ^ (n >> 6)) & (NB - 1);
    atomicAdd(&pool[batch[n] * NB + bk], dinv[n] * acc);
  }
}

// per-graph counts via binary search on the SORTED batch array; reduce pool buckets
__global__ void k_final(const float* __restrict__ pool, const int* __restrict__ batch,
                        const float* __restrict__ b2, const float* __restrict__ Wlin,
                        const float* __restrict__ blin, float* __restrict__ out) {
  int g = threadIdx.x;  // 256 threads
  if (g < NG) {
    int lo = 0, hi = NN;
    while (lo < hi) { int m = (lo + hi) >> 1; if (batch[m] < g) lo = m + 1; else hi = m; }
    int lb = lo;
    hi = NN;
    while (lo < hi) { int m = (lo + hi) >> 1; if (batch[m] < g + 1) lo = m + 1; else hi = m; }
    float cs = (float)(lo - lb);
    float cc = blin[0];
    for (int o = 0; o < HID; ++o) cc += b2[o] * Wlin[o];
    float ps = 0.f;
    for (int b = 0; b < NB; ++b) ps += pool[g * NB + b];
    out[g] = ps / fmaxf(cs, 1.0f) + cc;
  }
}

// ---------------- launch ----------------

extern "C" void kernel_launch(void* const* d_in, const int* in_sizes, int n_in,
                              void* d_out, int out_size, void* d_ws, size_t ws_size,
                              hipStream_t stream) {
  const float* x     = (const float*)d_in[0];
  const int*   ei    = (const int*)d_in[1];
  const float* w     = (const float*)d_in[2];
  const int*   batch = (const int*)d_in[3];
  const float* W1    = (const float*)d_in[4];
  const float* b1    = (const float*)d_in[5];
  const float* W2    = (const float*)d_in[6];
  const float* b2    = (const float*)d_in[7];
  const float* Wlin  = (const float*)d_in[8];
  const float* blin  = (const float*)d_in[9];
  float* out = (float*)d_out;

  const int* row = ei;
  const int* col = ei + NE;

  // workspace layout (32B-aligned chunks)
  char* p = (char*)d_ws;
  int2*  elist  = (int2*)p;  p += sizeof(int2) * (size_t)NBKT * CAP;  // 16.0 MB
  int2*  elist2 = (int2*)p;  p += sizeof(int2) * (size_t)NBKT * CAP;  // 16.0 MB
  HRow*  xsh    = (HRow*)p;  p += sizeof(HRow) * NN;                  // 3.2 MB
  int*   gcur   = (int*)p;   p += sizeof(int) * 512;
  int*   offs   = (int*)p;   p += sizeof(int) * NN;
  int*   cnt_in = (int*)p;   p += sizeof(int) * NN;
  float* dinv   = (float*)p; p += sizeof(float) * NN;
  float* ss     = (float*)p; p += sizeof(float) * NN;
  float* vbuf   = (float*)p; p += sizeof(float) * HID;
  float* pool   = (float*)p; p += sizeof(float) * NG * NB;

  const int gN4 = (NN + 63) / 64;    // 1563 blocks for 4-lane-per-node kernels

  hipLaunchKernelGGL(k_zero,    dim3(66),   dim3(256), 0, stream, pool, gcur, W2, Wlin, vbuf);
  hipLaunchKernelGGL(k_fillb2,  dim3(FB),   dim3(512), 0, stream, row, col, w, gcur, elist);
  hipLaunchKernelGGL(k_sortdeg, dim3(NBKT), dim3(512), 0, stream, gcur, elist, x,
                     elist2, offs, cnt_in, dinv, xsh);
  hipLaunchKernelGGL(k_gaxss,   dim3(gN4),  dim3(256), 0, stream, offs, cnt_in, elist2, xsh,
                     x, dinv, W1, b1, vbuf, ss);
  hipLaunchKernelGGL(k_gpool,   dim3(gN4),  dim3(256), 0, stream, offs, cnt_in, elist2, ss,
                     dinv, batch, pool);
  hipLaunchKernelGGL(k_final,   dim3(1),    dim3(256), 0, stream, pool, batch, b2, Wlin, blin, out);
}

// Round 13
// 100.186 us; speedup vs baseline: 1.1635x; 1.1005x over previous
//
#include <hip/hip_runtime.h>
#include <hip/hip_fp16.h>

#define NN 100000
#define NE 1600000
#define NG 256
#define FIN 10
#define HID 128
#define NB 64          // pool buckets per graph
#define NBKT 391       // coarse buckets of 256 nodes: ceil(NN/256)
#define FB 500         // fill blocks
#define EPB (NE / FB)  // 3200 edges per block (exact)
#define CAP 5120       // fixed bucket capacity (mean 4092, sigma 64 -> 16 sigma)

struct alignas(32) HRow { __half h[16]; };  // fp16 xs row; 10 used, 32B aligned

// ---------------- kernels ----------------

// zero pool + bucket cursors; block 65 computes v = W2 @ Wlin
__global__ void k_zero(float* __restrict__ pool, int* __restrict__ gcur,
                       const float* __restrict__ W2, const float* __restrict__ Wlin,
                       float* __restrict__ vbuf) {
  int t = threadIdx.x, b = blockIdx.x;
  if (b < 64) pool[b * 256 + t] = 0.f;
  if (b == 64) { for (int k = t; k < NBKT; k += 256) gcur[k] = 0; }
  if (b == 65 && t < HID) {
    float a = 0.f;
    for (int o = 0; o < HID; ++o) a += W2[t * HID + o] * Wlin[o];
    vbuf[t] = a;
  }
}

// single-pass bucketing: LDS-stage edges + LDS hist, claim per-bucket base via one
// global atomic per (block,bucket), scatter from LDS into fixed bucket regions.
// pack (dst&255) into src's spare bits (src < 2^17)
__global__ void __launch_bounds__(512)
k_fillb2(const int* __restrict__ row, const int* __restrict__ col,
         const float* __restrict__ w, int* __restrict__ gcur,
         int2* __restrict__ elist) {
  __shared__ int2 ebuf[EPB];       // 25.6 KB
  __shared__ short sbkt[EPB];      // 6.4 KB
  __shared__ int h[NBKT];
  __shared__ int base[NBKT];
  __shared__ int cur[NBKT];
  int t = threadIdx.x;
  for (int k = t; k < NBKT; k += 512) { h[k] = 0; cur[k] = 0; }
  __syncthreads();
  int gb = blockIdx.x * EPB;
  for (int i = t; i < EPB; i += 512) {
    int e = gb + i;
    int c = col[e];
    ebuf[i] = make_int2(row[e] | ((c & 255) << 17), __float_as_int(w[e]));
    sbkt[i] = (short)(c >> 8);
    atomicAdd(&h[c >> 8], 1);
  }
  __syncthreads();
  for (int k = t; k < NBKT; k += 512) {
    int hv = h[k];
    base[k] = hv ? atomicAdd(&gcur[k], hv) : 0;
  }
  __syncthreads();
  for (int i = t; i < EPB; i += 512) {
    int bkt = sbkt[i];
    int p = atomicAdd(&cur[bkt], 1);
    elist[(size_t)bkt * CAP + base[bkt] + p] = ebuf[i];
  }
}

// per-bucket: weighted in-degree via LDS -> dinv; xsh row = fp16(dinv*x), 32B padded
__global__ void __launch_bounds__(512)
k_degxs(const int* __restrict__ gcur, const int2* __restrict__ elist,
        const float* __restrict__ x, float* __restrict__ dinv,
        HRow* __restrict__ xsh) {
  __shared__ float wsum[256];
  int k = blockIdx.x, t = threadIdx.x;
  size_t base = (size_t)k * CAP;
  int tot = gcur[k];
  if (t < 256) wsum[t] = 0.f;
  __syncthreads();
  for (int i = t; i < tot; i += 512) {
    int2 ew = elist[base + i];
    atomicAdd(&wsum[(ew.x >> 17) & 255], __int_as_float(ew.y));
  }
  __syncthreads();
  int n = (k << 8) + t;
  if (t < 256 && n < NN) {
    float di = rsqrtf(1.f + wsum[t]);
    dinv[n] = di;
    HRow r;
#pragma unroll
    for (int f = 0; f < FIN; ++f) r.h[f] = __float2half(di * x[n * FIN + f]);
#pragma unroll
    for (int f = FIN; f < 16; ++f) r.h[f] = __float2half(0.f);
    xsh[n] = r;
  }
}

// per-bucket: counting-sort edges into LDS (node-contiguous segments), then
// 4-lane-per-node gather from LDS + fused dense layer -> ss
__global__ void __launch_bounds__(1024)
k_gaxsort(const int* __restrict__ gcur, const int2* __restrict__ elist,
          const HRow* __restrict__ xsh, const float* __restrict__ x,
          const float* __restrict__ dinv, const float* __restrict__ W1,
          const float* __restrict__ b1, const float* __restrict__ vbuf,
          float* __restrict__ ss) {
  __shared__ int2 ebufS[CAP];      // 40 KB: node-sorted edges
  __shared__ float W1s[FIN * HID];
  __shared__ float b1s[HID];
  __shared__ float vs[HID];
  __shared__ int cnt[256];
  __shared__ int tmp[256];
  __shared__ int cur[256];
  __shared__ int off[256];
  int k = blockIdx.x, t = threadIdx.x;
  size_t base = (size_t)k * CAP;
  int tot = gcur[k];
  if (t < 256) cnt[t] = 0;
  for (int j = t; j < FIN * HID; j += 1024) W1s[j] = W1[j];
  if (t < HID) { b1s[t] = b1[t]; vs[t] = vbuf[t]; }
  __syncthreads();
  for (int i = t; i < tot; i += 1024)
    atomicAdd(&cnt[(elist[base + i].x >> 17) & 255], 1);
  __syncthreads();
  int v = (t < 256) ? cnt[t] : 0;
  if (t < 256) tmp[t] = v;
  __syncthreads();
  for (int o = 1; o < 256; o <<= 1) {
    int u = (t >= o && t < 256) ? tmp[t - o] : 0;
    __syncthreads();
    if (t < 256) tmp[t] += u;
    __syncthreads();
  }
  if (t < 256) { off[t] = tmp[t] - v; cur[t] = tmp[t] - v; }
  __syncthreads();
  for (int i = t; i < tot; i += 1024) {
    int2 ew = elist[base + i];
    int l = (ew.x >> 17) & 255;
    int p = atomicAdd(&cur[l], 1);
    ebufS[p] = ew;
  }
  __syncthreads();
  int node = t >> 2, l = t & 3;
  int n = (k << 8) + node;
  if (n >= NN) return;
  int o = off[node], cn = cnt[node];
  float acc[FIN];
#pragma unroll
  for (int f = 0; f < FIN; ++f) acc[f] = 0.f;
  for (int kk = l; kk < cn; kk += 4) {
    int2 ew = ebufS[o + kk];
    float wt = __int_as_float(ew.y);
    const uint4* xp = (const uint4*)(xsh + (ew.x & 0x1FFFF));
    uint4 u0 = xp[0];
    unsigned u4 = ((const unsigned*)xp)[4];
    float2 p0 = __half22float2(*(const __half2*)&u0.x);
    float2 p1 = __half22float2(*(const __half2*)&u0.y);
    float2 p2 = __half22float2(*(const __half2*)&u0.z);
    float2 p3 = __half22float2(*(const __half2*)&u0.w);
    float2 p4 = __half22float2(*(const __half2*)&u4);
    acc[0] += wt * p0.x; acc[1] += wt * p0.y;
    acc[2] += wt * p1.x; acc[3] += wt * p1.y;
    acc[4] += wt * p2.x; acc[5] += wt * p2.y;
    acc[6] += wt * p3.x; acc[7] += wt * p3.y;
    acc[8] += wt * p4.x; acc[9] += wt * p4.y;
  }
#pragma unroll
  for (int f = 0; f < FIN; ++f) {
    acc[f] += __shfl_xor(acc[f], 1);
    acc[f] += __shfl_xor(acc[f], 2);
  }
  float di = dinv[n];
  float axr[FIN];
#pragma unroll
  for (int f = 0; f < FIN; ++f) axr[f] = di * (acc[f] + di * x[n * FIN + f]);
  float s = 0.f;
  for (int j = 0; j < HID / 4; ++j) {
    int h = j * 4 + l;
    float u = b1s[h];
#pragma unroll
    for (int f = 0; f < FIN; ++f) u += axr[f] * W1s[f * HID + h];
    s += fmaxf(u, 0.f) * vs[h];
  }
  s += __shfl_xor(s, 1);
  s += __shfl_xor(s, 2);
  if (l == 0) ss[n] = di * s;
}

// per-bucket: per-edge scalar LDS accumulate keyed by dst-local, then one pool
// atomic per node: pool[batch[n]] += dinv_n * ( ss[n] + sum_e w_e * ss[src] )
__global__ void __launch_bounds__(512)
k_gpool2(const int* __restrict__ gcur, const int2* __restrict__ elist,
         const float* __restrict__ ss, const float* __restrict__ dinv,
         const int* __restrict__ batch, float* __restrict__ pool) {
  __shared__ float accs[256];
  int k = blockIdx.x, t = threadIdx.x;
  size_t base = (size_t)k * CAP;
  int tot = gcur[k];
  if (t < 256) accs[t] = 0.f;
  __syncthreads();
  for (int i = t; i < tot; i += 512) {
    int2 ew = elist[base + i];
    atomicAdd(&accs[(ew.x >> 17) & 255], __int_as_float(ew.y) * ss[ew.x & 0x1FFFF]);
  }
  __syncthreads();
  int n = (k << 8) + t;
  if (t < 256 && n < NN) {
    float val = dinv[n] * (ss[n] + accs[t]);
    int bk = (t ^ k) & (NB - 1);
    atomicAdd(&pool[batch[n] * NB + bk], val);
  }
}

// per-graph counts via binary search on the SORTED batch array; reduce pool buckets
__global__ void k_final(const float* __restrict__ pool, const int* __restrict__ batch,
                        const float* __restrict__ b2, const float* __restrict__ Wlin,
                        const float* __restrict__ blin, float* __restrict__ out) {
  int g = threadIdx.x;  // 256 threads
  if (g < NG) {
    int lo = 0, hi = NN;
    while (lo < hi) { int m = (lo + hi) >> 1; if (batch[m] < g) lo = m + 1; else hi = m; }
    int lb = lo;
    hi = NN;
    while (lo < hi) { int m = (lo + hi) >> 1; if (batch[m] < g + 1) lo = m + 1; else hi = m; }
    float cs = (float)(lo - lb);
    float cc = blin[0];
    for (int o = 0; o < HID; ++o) cc += b2[o] * Wlin[o];
    float ps = 0.f;
    for (int b = 0; b < NB; ++b) ps += pool[g * NB + b];
    out[g] = ps / fmaxf(cs, 1.0f) + cc;
  }
}

// ---------------- launch ----------------

extern "C" void kernel_launch(void* const* d_in, const int* in_sizes, int n_in,
                              void* d_out, int out_size, void* d_ws, size_t ws_size,
                              hipStream_t stream) {
  const float* x     = (const float*)d_in[0];
  const int*   ei    = (const int*)d_in[1];
  const float* w     = (const float*)d_in[2];
  const int*   batch = (const int*)d_in[3];
  const float* W1    = (const float*)d_in[4];
  const float* b1    = (const float*)d_in[5];
  const float* W2    = (const float*)d_in[6];
  const float* b2    = (const float*)d_in[7];
  const float* Wlin  = (const float*)d_in[8];
  const float* blin  = (const float*)d_in[9];
  float* out = (float*)d_out;

  const int* row = ei;
  const int* col = ei + NE;

  // workspace layout (32B-aligned chunks)
  char* p = (char*)d_ws;
  int2*  elist = (int2*)p;  p += sizeof(int2) * (size_t)NBKT * CAP;  // 16.0 MB
  HRow*  xsh   = (HRow*)p;  p += sizeof(HRow) * NN;                  // 3.2 MB
  int*   gcur  = (int*)p;   p += sizeof(int) * 512;
  float* dinv  = (float*)p; p += sizeof(float) * NN;
  float* ss    = (float*)p; p += sizeof(float) * NN;
  float* vbuf  = (float*)p; p += sizeof(float) * HID;
  float* pool  = (float*)p; p += sizeof(float) * NG * NB;

  hipLaunchKernelGGL(k_zero,    dim3(66),   dim3(256),  0, stream, pool, gcur, W2, Wlin, vbuf);
  hipLaunchKernelGGL(k_fillb2,  dim3(FB),   dim3(512),  0, stream, row, col, w, gcur, elist);
  hipLaunchKernelGGL(k_degxs,   dim3(NBKT), dim3(512),  0, stream, gcur, elist, x, dinv, xsh);
  hipLaunchKernelGGL(k_gaxsort, dim3(NBKT), dim3(1024), 0, stream, gcur, elist, xsh, x,
                     dinv, W1, b1, vbuf, ss);
  hipLaunchKernelGGL(k_gpool2,  dim3(NBKT), dim3(512),  0, stream, gcur, elist, ss,
                     dinv, batch, pool);
  hipLaunchKernelGGL(k_final,   dim3(1),    dim3(256),  0, stream, pool, batch, b2, Wlin, blin, out);
}